// Round 3
// baseline (526.488 us; speedup 1.0000x reference)
//
#include <hip/hip_runtime.h>
#include <hip/hip_cooperative_groups.h>
#include <hip/hip_bf16.h>
#include <stdint.h>

namespace cg = cooperative_groups;

using bf16 = __hip_bfloat16;
typedef __attribute__((ext_vector_type(8))) short short8;
typedef __attribute__((ext_vector_type(4))) float floatx4;

#define DD 32
#define DL3 32768      // 32^3
#define BATCH 256
#define NK 1024        // 32*32

// GEMM tile geometry: 256x128 block, BK=64, 8 waves = 2M x 2N x 2K
#define NKT 16                 // K-tiles of 64 in K=1024
#define A_ELEM 16384           // A region per buffer: 256*64 bf16 = 32KB
#define BUF_ELEM 24576         // 48KB per buffer (bf16 elems)
#define LDS_BYTES 147456       // 3 buffers * 48KB

// async global->LDS, 16B per lane (wave-uniform base + lane*16 layout respected)
__device__ __forceinline__ void load16(const void* g, void* l) {
  __builtin_amdgcn_global_load_lds((const __attribute__((address_space(1))) void*)g,
                                   (__attribute__((address_space(3))) void*)l,
                                   16, 0, 0);
}

// dst[b][v][f][u] = x[b][u][v][f]  (fp32 -> bf16)
__global__ __launch_bounds__(256) void prep_x(const float* __restrict__ x, bf16* __restrict__ dst) {
  int b = blockIdx.x >> 5, v = blockIdx.x & 31;
  __shared__ float tile[32][33];
  const float* xb = x + (size_t)b * DL3 + v * DD;
  int t = threadIdx.x;
#pragma unroll
  for (int it = 0; it < 4; ++it) {
    int u = (t >> 5) + it * 8, f = t & 31;
    tile[u][f] = xb[u * NK + f];
  }
  __syncthreads();
  bf16* db = dst + (size_t)b * DL3 + v * NK;
#pragma unroll
  for (int it = 0; it < 4; ++it) {
    int f = (t >> 5) + it * 8, u = t & 31;
    db[f * DD + u] = __float2bfloat16(tile[u][f]);
  }
}

// nodeT[i][n][v*32+u] = node[i][u*32+v][n]  (fp32 -> bf16)
__global__ __launch_bounds__(256) void prep_nodes(const float* __restrict__ nodes, bf16* __restrict__ dst) {
  int id = blockIdx.x;
  int nb = id & 31, kb = (id >> 5) & 31, i = id >> 10;
  const float* src = nodes + (size_t)i * 1048576;
  bf16* d = dst + (size_t)i * 1048576;
  __shared__ float tile[32][33];
  int t = threadIdx.x;
#pragma unroll
  for (int it = 0; it < 4; ++it) {
    int u = (t >> 5) + it * 8, j = t & 31;
    tile[u][j] = src[(size_t)(u * 32 + kb) * 1024 + nb * 32 + j];
  }
  __syncthreads();
#pragma unroll
  for (int it = 0; it < 4; ++it) {
    int j = (t >> 5) + it * 8, u = t & 31;
    d[(size_t)(nb * 32 + j) * 1024 + kb * 32 + u] = __float2bfloat16(tile[u][j]);
  }
}

// ---- shared inner-loop body (round-2 verified structure) ----------------
// C[(b*32+f)][n] = sum_k A[(b,f)][k] * Bt[k][n]
// 256x128 tile, 8 waves = 2M x 2N x 2K; 3-deep pipeline, counted vmcnt(6),
// T2 XOR-swizzle both-sides, T5 setprio, m89 C/D layout.

// All 6 steps in one cooperative kernel; grid=256 blocks (1/CU), 512 thr.
__global__ __launch_bounds__(512, 2) void entangler_chain(
    bf16* __restrict__ buf0, const bf16* __restrict__ nodeT,
    bf16* __restrict__ buf1, float* __restrict__ out, const float* __restrict__ bias) {
  extern __shared__ char smem[];
  bf16* lds = (bf16*)smem;

  const int t = threadIdx.x;
  const int lane = t & 63;
  const int lane16 = lane & 15, quad = lane >> 4;
  const int w = t >> 6;
  const int wm = (w >> 2) & 1, wn = (w >> 1) & 1, wk = w & 1;
  const int sel = (lane16 >> 1) & 3;
  const int qs = (quad ^ sel) * 8;
  const int xt = blockIdx.x & 31, yt = blockIdx.x >> 5;
  const int b0 = xt * 8;                   // 8 batch elems per 256-row tile
  const int N0 = yt * 128;

  // read-side element offsets within a buffer (kk = wk fixed per wave)
  const int aRd = wk * 8192 + (wm * 128 + lane16) * 32 + qs;
  const int bRd = A_ELEM + wk * 4096 + (wn * 64 + lane16) * 32 + qs;

  // stage-side: physical slot P linear; logical L = P ^ swz -> global src addr
  int aOff[4], aLds[4], bOff[2], bLds[2];
#pragma unroll
  for (int r = 0; r < 4; ++r) {
    int P = (r * 512 + t) * 16;
    int L = P ^ (((P >> 7) & 3) << 4);
    int kk = L >> 14, m = (L >> 6) & 255, u0 = (L & 63) >> 1;
    aOff[r] = (b0 + (m >> 5)) * DL3 + kk * NK + (m & 31) * 32 + u0;
    aLds[r] = P >> 1;
  }
#pragma unroll
  for (int r = 0; r < 2; ++r) {
    int P = (r * 512 + t) * 16;
    int L = P ^ (((P >> 7) & 3) << 4);
    int kk = L >> 13, n = (L >> 6) & 127, u0 = (L & 63) >> 1;
    bOff[r] = (N0 + n) * NK + kk * 32 + u0;
    bLds[r] = A_ELEM + (P >> 1);
  }

  cg::grid_group grid = cg::this_grid();

#pragma unroll 1
  for (int s = 0; s < 6; ++s) {
    const bf16* Ain = (s & 1) ? buf1 : buf0;
    bf16* Cw = (s & 1) ? buf0 : buf1;
    const bf16* Bs = nodeT + (size_t)s * 1048576;
    const bool FIN = (s == 5);

    floatx4 acc[8][4];
#pragma unroll
    for (int i = 0; i < 8; ++i)
#pragma unroll
      for (int j = 0; j < 4; ++j)
        acc[i][j] = (floatx4){0.f, 0.f, 0.f, 0.f};

    bf16* pCur = lds;
    bf16* pNxt = lds + BUF_ELEM;
    bf16* pThd = lds + 2 * BUF_ELEM;

    // Prologue: stage K-tiles 0,1 into buffers 0,1 (12 loads in flight).
#pragma unroll
    for (int r = 0; r < 4; ++r) load16(Ain + aOff[r], pCur + aLds[r]);
#pragma unroll
    for (int r = 0; r < 2; ++r) load16(Bs + bOff[r], pCur + bLds[r]);
#pragma unroll
    for (int r = 0; r < 4; ++r) load16(Ain + aOff[r] + 2048, pNxt + aLds[r]);
#pragma unroll
    for (int r = 0; r < 2; ++r) load16(Bs + bOff[r] + 64, pNxt + bLds[r]);
    asm volatile("s_waitcnt vmcnt(6)" ::: "memory");   // tile 0 landed
    __builtin_amdgcn_s_barrier();
    asm volatile("" ::: "memory");

#pragma unroll 1
    for (int kt = 0; kt < NKT; ++kt) {
      // ds_read this wave's kk-half fragments (12 x b128, swizzled)
      short8 af[8], bfr[4];
#pragma unroll
      for (int i = 0; i < 8; ++i) af[i] = *(const short8*)(pCur + aRd + i * 512);
#pragma unroll
      for (int j = 0; j < 4; ++j) bfr[j] = *(const short8*)(pCur + bRd + j * 512);
      // issue stage(kt+2) into third buffer
      if (kt < NKT - 2) {
#pragma unroll
        for (int r = 0; r < 4; ++r) load16(Ain + aOff[r] + (kt + 2) * 2048, pThd + aLds[r]);
#pragma unroll
        for (int r = 0; r < 2; ++r) load16(Bs + bOff[r] + (kt + 2) * 64, pThd + bLds[r]);
      }
      asm volatile("" ::: "memory");
      __builtin_amdgcn_s_barrier();              // B1: align wave phases
      asm volatile("" ::: "memory");
      __builtin_amdgcn_s_setprio(1);
#pragma unroll
      for (int i = 0; i < 8; ++i)
#pragma unroll
        for (int j = 0; j < 4; ++j)
          acc[i][j] = __builtin_amdgcn_mfma_f32_16x16x32_bf16(af[i], bfr[j], acc[i][j], 0, 0, 0);
      __builtin_amdgcn_s_setprio(0);
      if (kt < NKT - 2) {
        asm volatile("s_waitcnt vmcnt(6)" ::: "memory");   // tile kt+1 landed
      } else if (kt == NKT - 2) {
        asm volatile("s_waitcnt vmcnt(0)" ::: "memory");   // last tile landed
      }
      if (kt < NKT - 1) {
        __builtin_amdgcn_s_barrier();            // B2: publish tile kt+1
        asm volatile("" ::: "memory");
      }
      // rotate buffers
      bf16* tmp = pCur; pCur = pNxt; pNxt = pThd; pThd = tmp;
    }

    // Cross-wave K-reduction (wk=1 dumps, wk=0 adds + writes C)
    __syncthreads();   // vmcnt fully drained at kt==14
    float* red = (float*)smem;
    const int pair = (wm << 1) | wn;
    if (wk == 1) {
      float* dst = red + pair * 8192;
#pragma unroll
      for (int i = 0; i < 8; ++i)
#pragma unroll
        for (int j = 0; j < 4; ++j)
          *(floatx4*)(dst + ((i * 4 + j) * 64 + lane) * 4) = acc[i][j];
    }
    __syncthreads();
    if (wk == 0) {
      const float* src = red + pair * 8192;
      const int R0 = xt * 256;
#pragma unroll
      for (int i = 0; i < 8; ++i) {
#pragma unroll
        for (int j = 0; j < 4; ++j) {
          floatx4 p = *(const floatx4*)(src + ((i * 4 + j) * 64 + lane) * 4);
          acc[i][j] += p;
#pragma unroll
          for (int r = 0; r < 4; ++r) {
            // C/D layout: col = lane&15, row = quad*4 + reg  [m89-verified]
            int row = R0 + wm * 128 + i * 16 + quad * 4 + r;
            int col = N0 + wn * 64 + j * 16 + lane16;
            if (FIN) {
              float v = acc[i][j][r] + bias[(row & 31) * 1024 + col];
              out[(size_t)row * 1024 + col] = fmaxf(v, 0.f);
            } else {
              Cw[(size_t)row * 1024 + col] = __float2bfloat16(acc[i][j][r]);
            }
          }
        }
      }
    }
    if (s < 5) grid.sync();   // all C-writes visible before next step's A-reads
  }
}

// ---- non-cooperative fallback (round-2 kernel, 6 dispatches) -------------
template <bool FINAL>
__global__ __launch_bounds__(512, 2) void entangler_gemm(
    const bf16* __restrict__ A, const bf16* __restrict__ Bn,
    bf16* __restrict__ Cb, float* __restrict__ Cf, const float* __restrict__ bias) {
  extern __shared__ char smem[];
  bf16* lds = (bf16*)smem;
  const int t = threadIdx.x;
  const int lane = t & 63;
  const int lane16 = lane & 15, quad = lane >> 4;
  const int w = t >> 6;
  const int wm = (w >> 2) & 1, wn = (w >> 1) & 1, wk = w & 1;
  const int sel = (lane16 >> 1) & 3;
  const int qs = (quad ^ sel) * 8;
  const int b0 = blockIdx.x * 8;
  const int N0 = blockIdx.y * 128;
  const int aRd = wk * 8192 + (wm * 128 + lane16) * 32 + qs;
  const int bRd = A_ELEM + wk * 4096 + (wn * 64 + lane16) * 32 + qs;
  int aOff[4], aLds[4], bOff[2], bLds[2];
#pragma unroll
  for (int r = 0; r < 4; ++r) {
    int P = (r * 512 + t) * 16;
    int L = P ^ (((P >> 7) & 3) << 4);
    int kk = L >> 14, m = (L >> 6) & 255, u0 = (L & 63) >> 1;
    aOff[r] = (b0 + (m >> 5)) * DL3 + kk * NK + (m & 31) * 32 + u0;
    aLds[r] = P >> 1;
  }
#pragma unroll
  for (int r = 0; r < 2; ++r) {
    int P = (r * 512 + t) * 16;
    int L = P ^ (((P >> 7) & 3) << 4);
    int kk = L >> 13, n = (L >> 6) & 127, u0 = (L & 63) >> 1;
    bOff[r] = (N0 + n) * NK + kk * 32 + u0;
    bLds[r] = A_ELEM + (P >> 1);
  }
  floatx4 acc[8][4];
#pragma unroll
  for (int i = 0; i < 8; ++i)
#pragma unroll
    for (int j = 0; j < 4; ++j)
      acc[i][j] = (floatx4){0.f, 0.f, 0.f, 0.f};
  bf16* pCur = lds; bf16* pNxt = lds + BUF_ELEM; bf16* pThd = lds + 2 * BUF_ELEM;
#pragma unroll
  for (int r = 0; r < 4; ++r) load16(A + aOff[r], pCur + aLds[r]);
#pragma unroll
  for (int r = 0; r < 2; ++r) load16(Bn + bOff[r], pCur + bLds[r]);
#pragma unroll
  for (int r = 0; r < 4; ++r) load16(A + aOff[r] + 2048, pNxt + aLds[r]);
#pragma unroll
  for (int r = 0; r < 2; ++r) load16(Bn + bOff[r] + 64, pNxt + bLds[r]);
  asm volatile("s_waitcnt vmcnt(6)" ::: "memory");
  __builtin_amdgcn_s_barrier();
  asm volatile("" ::: "memory");
#pragma unroll 1
  for (int kt = 0; kt < NKT; ++kt) {
    short8 af[8], bfr[4];
#pragma unroll
    for (int i = 0; i < 8; ++i) af[i] = *(const short8*)(pCur + aRd + i * 512);
#pragma unroll
    for (int j = 0; j < 4; ++j) bfr[j] = *(const short8*)(pCur + bRd + j * 512);
    if (kt < NKT - 2) {
#pragma unroll
      for (int r = 0; r < 4; ++r) load16(A + aOff[r] + (kt + 2) * 2048, pThd + aLds[r]);
#pragma unroll
      for (int r = 0; r < 2; ++r) load16(Bn + bOff[r] + (kt + 2) * 64, pThd + bLds[r]);
    }
    asm volatile("" ::: "memory");
    __builtin_amdgcn_s_barrier();
    asm volatile("" ::: "memory");
    __builtin_amdgcn_s_setprio(1);
#pragma unroll
    for (int i = 0; i < 8; ++i)
#pragma unroll
      for (int j = 0; j < 4; ++j)
        acc[i][j] = __builtin_amdgcn_mfma_f32_16x16x32_bf16(af[i], bfr[j], acc[i][j], 0, 0, 0);
    __builtin_amdgcn_s_setprio(0);
    if (kt < NKT - 2) {
      asm volatile("s_waitcnt vmcnt(6)" ::: "memory");
    } else if (kt == NKT - 2) {
      asm volatile("s_waitcnt vmcnt(0)" ::: "memory");
    }
    if (kt < NKT - 1) {
      __builtin_amdgcn_s_barrier();
      asm volatile("" ::: "memory");
    }
    bf16* tmp = pCur; pCur = pNxt; pNxt = pThd; pThd = tmp;
  }
  __syncthreads();
  float* red = (float*)smem;
  const int pair = (wm << 1) | wn;
  if (wk == 1) {
    float* dst = red + pair * 8192;
#pragma unroll
    for (int i = 0; i < 8; ++i)
#pragma unroll
      for (int j = 0; j < 4; ++j)
        *(floatx4*)(dst + ((i * 4 + j) * 64 + lane) * 4) = acc[i][j];
  }
  __syncthreads();
  if (wk == 0) {
    const float* src = red + pair * 8192;
    const int R0 = blockIdx.x * 256;
#pragma unroll
    for (int i = 0; i < 8; ++i) {
#pragma unroll
      for (int j = 0; j < 4; ++j) {
        floatx4 p = *(const floatx4*)(src + ((i * 4 + j) * 64 + lane) * 4);
        acc[i][j] += p;
#pragma unroll
        for (int r = 0; r < 4; ++r) {
          int row = R0 + wm * 128 + i * 16 + quad * 4 + r;
          int col = N0 + wn * 64 + j * 16 + lane16;
          if (FINAL) {
            float v = acc[i][j][r] + bias[(row & 31) * 1024 + col];
            Cf[(size_t)row * 1024 + col] = fmaxf(v, 0.f);
          } else {
            Cb[(size_t)row * 1024 + col] = __float2bfloat16(acc[i][j][r]);
          }
        }
      }
    }
  }
}

extern "C" void kernel_launch(void* const* d_in, const int* in_sizes, int n_in,
                              void* d_out, int out_size, void* d_ws, size_t ws_size,
                              hipStream_t stream) {
  const float* x     = (const float*)d_in[0];   // (256, 32768) fp32
  const float* nodes = (const float*)d_in[1];   // (6, 32,32,32,32) fp32
  const float* bias  = (const float*)d_in[2];   // (32768,) fp32
  float* out = (float*)d_out;                   // (256, 32768) fp32

  bf16* buf0  = (bf16*)d_ws;
  bf16* buf1  = buf0 + (size_t)BATCH * DL3;
  bf16* nodeT = buf1 + (size_t)BATCH * DL3;

  static bool attr_done = false;
  if (!attr_done) {
    hipFuncSetAttribute((const void*)entangler_chain,
                        hipFuncAttributeMaxDynamicSharedMemorySize, LDS_BYTES);
    hipFuncSetAttribute((const void*)entangler_gemm<false>,
                        hipFuncAttributeMaxDynamicSharedMemorySize, LDS_BYTES);
    hipFuncSetAttribute((const void*)entangler_gemm<true>,
                        hipFuncAttributeMaxDynamicSharedMemorySize, LDS_BYTES);
    attr_done = true;
  }

  prep_x<<<dim3(BATCH * 32), dim3(256), 0, stream>>>(x, buf0);
  prep_nodes<<<dim3(6 * 1024), dim3(256), 0, stream>>>(nodes, nodeT);

  // cooperative fused chain (1 block/CU, 256 blocks): all 6 GEMMs + 5 grid syncs
  bf16* a_buf0 = buf0; const bf16* a_nodeT = nodeT; bf16* a_buf1 = buf1;
  float* a_out = out; const float* a_bias = bias;
  void* args[] = {&a_buf0, &a_nodeT, &a_buf1, &a_out, &a_bias};
  hipError_t e = hipLaunchCooperativeKernel((const void*)entangler_chain,
                                            dim3(256), dim3(512), args,
                                            LDS_BYTES, stream);
  if (e != hipSuccess) {
    // fallback: 6 separate dispatches (round-2 verified path)
    dim3 grid(32, 8), blk(512);
    entangler_gemm<false><<<grid, blk, LDS_BYTES, stream>>>(buf0, nodeT + (size_t)0 * 1048576, buf1, nullptr, nullptr);
    entangler_gemm<false><<<grid, blk, LDS_BYTES, stream>>>(buf1, nodeT + (size_t)1 * 1048576, buf0, nullptr, nullptr);
    entangler_gemm<false><<<grid, blk, LDS_BYTES, stream>>>(buf0, nodeT + (size_t)2 * 1048576, buf1, nullptr, nullptr);
    entangler_gemm<false><<<grid, blk, LDS_BYTES, stream>>>(buf1, nodeT + (size_t)3 * 1048576, buf0, nullptr, nullptr);
    entangler_gemm<false><<<grid, blk, LDS_BYTES, stream>>>(buf0, nodeT + (size_t)4 * 1048576, buf1, nullptr, nullptr);
    entangler_gemm<true ><<<grid, blk, LDS_BYTES, stream>>>(buf1, nodeT + (size_t)5 * 1048576, nullptr, out, bias);
  }
}

// Round 4
// 444.787 us; speedup vs baseline: 1.1837x; 1.1837x over previous
//
#include <hip/hip_runtime.h>
#include <hip/hip_bf16.h>
#include <stdint.h>

using bf16 = __hip_bfloat16;
typedef __attribute__((ext_vector_type(8))) short short8;
typedef __attribute__((ext_vector_type(4))) float floatx4;

#define DD 32
#define DL3 32768      // 32^3
#define BATCH 256
#define NK 1024        // 32*32
#define LDS_BYTES 131072   // 2 x 32768 bf16 state buffers

// nodeT[i][n][v*32+u] = node[i][u*32+v][n]  (fp32 -> bf16)
__global__ __launch_bounds__(256) void prep_nodes(const float* __restrict__ nodes, bf16* __restrict__ dst) {
  int id = blockIdx.x;
  int nb = id & 31, kb = (id >> 5) & 31, i = id >> 10;
  const float* src = nodes + (size_t)i * 1048576;
  bf16* d = dst + (size_t)i * 1048576;
  __shared__ float tile[32][33];
  int t = threadIdx.x;
#pragma unroll
  for (int it = 0; it < 4; ++it) {
    int u = (t >> 5) + it * 8, j = t & 31;
    tile[u][j] = src[(size_t)(u * 32 + kb) * 1024 + nb * 32 + j];
  }
  __syncthreads();
#pragma unroll
  for (int it = 0; it < 4; ++it) {
    int j = (t >> 5) + it * 8, u = t & 31;
    d[(size_t)(nb * 32 + j) * 1024 + kb * 32 + u] = __float2bfloat16(tile[u][j]);
  }
}

// Batch-resident chain: one block = one batch element, all 6 steps, no global sync.
// State (32 x 1024) ping-pongs between two 64KB LDS buffers (XOR-swizzled).
// Per step: GEMM  out[f][n] = sum_k state[f][k] * Bt_s[k][n]
//   state logical layout: idx = v*1024 + f*32 + u   (k = v*32+u)  [matches the
//   verified A-gather A[(b,f)][(v,u)] = mem[b][v][f][u] of previous rounds]
//   C-write logical layout: idx = f_out*1024 + n    [matches verified C-write]
// B streamed from L2 straight to registers (nodeT row-major [n][k]).
// 8 waves: wave w owns n in [w*128, (w+1)*128); all waves cover all 32 f-rows.
__global__ __launch_bounds__(512, 2) void entangler_batch(
    const float* __restrict__ x, const bf16* __restrict__ nodeT,
    float* __restrict__ out, const float* __restrict__ bias) {
  extern __shared__ char smem[];
  char* st0 = smem;                // 65536 B: state buffer A
  char* st1 = smem + 65536;        // 65536 B: state buffer B

  const int t = threadIdx.x;
  const int lane = t & 63;
  const int lane16 = lane & 15, quad = lane >> 4;
  const int w = t >> 6;
  const int b = blockIdx.x;

  // ---- init: state0[v*1024 + f*32 + u] = bf16(x[b][u*1024 + v*32 + f]) ----
  const float* xb = x + (size_t)b * DL3;
#pragma unroll
  for (int it = 0; it < 16; ++it) {
    int flat = it * 512 + t;                    // float4 granule of x row
    floatx4 vx = *(const floatx4*)(xb + flat * 4);
    int e0 = flat * 4;
    int f = e0 & 31, v = (e0 >> 5) & 31, u = e0 >> 10;
#pragma unroll
    for (int e = 0; e < 4; ++e) {
      int byte = (v * 1024 + (f + e) * 32 + u) * 2;
      byte ^= ((byte >> 7) & 3) << 4;           // LDS XOR-swizzle (both sides)
      *(bf16*)(st0 + byte) = __float2bfloat16(vx[e]);
    }
  }

  // per-lane B base pointers: row n = w*128 + j*16 + lane16, col base quad*8.
  // per-kc offset is kc*32 elems = kc*64 bytes -> fits the 13-bit imm offset.
  const bf16* pB[8];
#pragma unroll
  for (int j = 0; j < 8; ++j)
    pB[j] = nodeT + (size_t)(w * 128 + j * 16 + lane16) * 1024 + quad * 8;

  // A-frag swizzled base byte addrs: row f = i*16 + lane16, elems u = quad*8..+7.
  // byte = f*64 + quad*16 (+ kc*2048, swizzle-invariant: kc only touches bits>=11)
  int aAddr[2];
#pragma unroll
  for (int i = 0; i < 2; ++i) {
    int byte = ((i * 16 + lane16) * 32 + quad * 8) * 2;
    aAddr[i] = byte ^ (((byte >> 7) & 3) << 4);
  }

  char* sIn = st0;
  char* sOut = st1;
  __syncthreads();   // init visible to all waves

#pragma unroll 1
  for (int s = 0; s < 6; ++s) {
    floatx4 acc[2][8];
#pragma unroll
    for (int i = 0; i < 2; ++i)
#pragma unroll
      for (int j = 0; j < 8; ++j)
        acc[i][j] = (floatx4){0.f, 0.f, 0.f, 0.f};

    // K-loop: 32 chunks of 32. Distance-2 software pipeline on B (named bufs,
    // static indexing); compiler inserts counted vmcnt before each MFMA group.
    short8 b0[8], b1[8], af0[2], af1[2];
#pragma unroll
    for (int j = 0; j < 8; ++j) b0[j] = *(const short8*)(pB[j] + 0 * 32);
#pragma unroll 1
    for (int kc = 0; kc < 32; kc += 2) {
      // prefetch kc+1 into b1 while computing kc with b0
#pragma unroll
      for (int j = 0; j < 8; ++j) b1[j] = *(const short8*)(pB[j] + (kc + 1) * 32);
#pragma unroll
      for (int i = 0; i < 2; ++i)
        af0[i] = *(const short8*)(sIn + aAddr[i] + kc * 2048);
#pragma unroll
      for (int i = 0; i < 2; ++i)
#pragma unroll
        for (int j = 0; j < 8; ++j)
          acc[i][j] = __builtin_amdgcn_mfma_f32_16x16x32_bf16(af0[i], b0[j], acc[i][j], 0, 0, 0);
      // prefetch kc+2 into b0 while computing kc+1 with b1
      if (kc + 2 < 32) {
#pragma unroll
        for (int j = 0; j < 8; ++j) b0[j] = *(const short8*)(pB[j] + (kc + 2) * 32);
      }
#pragma unroll
      for (int i = 0; i < 2; ++i)
        af1[i] = *(const short8*)(sIn + aAddr[i] + (kc + 1) * 2048);
#pragma unroll
      for (int i = 0; i < 2; ++i)
#pragma unroll
        for (int j = 0; j < 8; ++j)
          acc[i][j] = __builtin_amdgcn_mfma_f32_16x16x32_bf16(af1[i], b1[j], acc[i][j], 0, 0, 0);
    }

    if (s < 5) {
      // epilogue -> LDS out buffer, logical idx = f_out*1024 + n, swizzled.
      // C/D layout: col = lane&15, row = quad*4 + reg  [m89-verified]
#pragma unroll
      for (int i = 0; i < 2; ++i) {
#pragma unroll
        for (int j = 0; j < 8; ++j) {
#pragma unroll
          for (int r = 0; r < 4; ++r) {
            int f = i * 16 + quad * 4 + r;
            int n = w * 128 + j * 16 + lane16;
            int byte = (f * 1024 + n) * 2;
            byte ^= ((byte >> 7) & 3) << 4;
            *(bf16*)(sOut + byte) = __float2bfloat16(acc[i][j][r]);
          }
        }
      }
      // advance node pointers to step s+1
#pragma unroll
      for (int j = 0; j < 8; ++j) pB[j] += 1048576;
      __syncthreads();   // publish new state; old state free to overwrite
      char* tmp = sIn; sIn = sOut; sOut = tmp;
    } else {
      // FINAL: out[b][f*1024+n] = relu(acc + bias[f*1024+n]), fp32 (full precision)
      float* ob = out + (size_t)b * DL3;
#pragma unroll
      for (int i = 0; i < 2; ++i) {
#pragma unroll
        for (int j = 0; j < 8; ++j) {
#pragma unroll
          for (int r = 0; r < 4; ++r) {
            int f = i * 16 + quad * 4 + r;
            int n = w * 128 + j * 16 + lane16;
            float v = acc[i][j][r] + bias[f * 1024 + n];
            ob[f * 1024 + n] = fmaxf(v, 0.f);
          }
        }
      }
    }
  }
}

extern "C" void kernel_launch(void* const* d_in, const int* in_sizes, int n_in,
                              void* d_out, int out_size, void* d_ws, size_t ws_size,
                              hipStream_t stream) {
  const float* x     = (const float*)d_in[0];   // (256, 32768) fp32
  const float* nodes = (const float*)d_in[1];   // (6, 32,32,32,32) fp32
  const float* bias  = (const float*)d_in[2];   // (32768,) fp32
  float* out = (float*)d_out;                   // (256, 32768) fp32

  // ws layout: nodeT 12MB only
  bf16* nodeT = (bf16*)d_ws;

  static bool attr_done = false;
  if (!attr_done) {
    hipFuncSetAttribute((const void*)entangler_batch,
                        hipFuncAttributeMaxDynamicSharedMemorySize, LDS_BYTES);
    attr_done = true;
  }

  prep_nodes<<<dim3(6 * 1024), dim3(256), 0, stream>>>(nodes, nodeT);
  entangler_batch<<<dim3(BATCH), dim3(512), LDS_BYTES, stream>>>(x, nodeT, out, bias);
}

// Round 6
// 255.704 us; speedup vs baseline: 2.0590x; 1.7395x over previous
//
#include <hip/hip_runtime.h>
#include <hip/hip_bf16.h>
#include <stdint.h>

using bf16 = __hip_bfloat16;
typedef __attribute__((ext_vector_type(8))) short short8;
typedef __attribute__((ext_vector_type(4))) float floatx4;

#define DD 32
#define DL3 32768      // 32^3
#define BATCH 256
#define NK 1024        // 32*32
#define LDS_BYTES 131072   // 2 x 64KB bf16 state buffers

// LDS swizzle (involution): bank bits 4,5 ^= byte bits 7,8; bits 5,6 ^= bits 13,14.
// Read side (byte = kc*2048 + f*64 + quad*16): bits7,8 = f1,f2 (lane-varying ok),
// bits13,14 = kc2,kc3 (uniform, harmless). Write side (byte = f*2048 + n*2):
// bits7,8 = n6,n7 (uniform), bits13,14 = f2,f3 = quad (spreads quads) -> 2-way free.
__device__ __forceinline__ int swz(int b) {
  return b ^ ((((b) >> 7) & 3) << 4) ^ ((((b) >> 13) & 3) << 5);
}

// nodeT[i][n][k] = node[i][u*32+v][n]  (k = v*32+u, fp32 -> bf16)  [proven]
__global__ __launch_bounds__(256) void prep_nodes(const float* __restrict__ nodes, bf16* __restrict__ dst) {
  int id = blockIdx.x;
  int nb = id & 31, kb = (id >> 5) & 31, i = id >> 10;
  const float* src = nodes + (size_t)i * 1048576;
  bf16* d = dst + (size_t)i * 1048576;
  __shared__ float tile[32][33];
  int t = threadIdx.x;
#pragma unroll
  for (int it = 0; it < 4; ++it) {
    int u = (t >> 5) + it * 8, j = t & 31;
    tile[u][j] = src[(size_t)(u * 32 + kb) * 1024 + nb * 32 + j];
  }
  __syncthreads();
#pragma unroll
  for (int it = 0; it < 4; ++it) {
    int j = (t >> 5) + it * 8, u = t & 31;
    d[(size_t)(nb * 32 + j) * 1024 + kb * 32 + u] = __float2bfloat16(tile[u][j]);
  }
}

// Frag-major permutation so GEMM B-loads are contiguous per wave:
// nodeTf granule o = [nt 0..63][lane 0..63], 16B per lane:
//   lane (lane16,quad) holds B[n = nt*16+lane16][k = kc*32+quad*8 .. +7]
__global__ __launch_bounds__(256) void prep_frag(const bf16* __restrict__ nodeT, bf16* __restrict__ nodeTf) {
  int id = blockIdx.x;            // i*32 + kc
  int kc = id & 31, i = id >> 5;
  const bf16* src = nodeT + (size_t)i * 1048576 + kc * 32;
  bf16* dst = nodeTf + (size_t)i * 1048576 + (size_t)kc * 32768;
  int t = threadIdx.x;
#pragma unroll
  for (int it = 0; it < 16; ++it) {
    int o = it * 256 + t;
    int lane = o & 63, nt = o >> 6;
    int n = nt * 16 + (lane & 15), q = lane >> 4;
    short8 vv = *(const short8*)(src + (size_t)n * 1024 + q * 8);
    *(short8*)(dst + (size_t)o * 8) = vv;       // coalesced 16B/lane
  }
}

#define LDB(buf, kc_) { const char* _p = Bs + (size_t)(kc_) * 65536;          \
  _Pragma("unroll") for (int _j = 0; _j < 8; ++_j)                            \
    buf[_j] = *(const short8*)(_p + _j * 1024); }

#define LDA(af_, kc_) { _Pragma("unroll") for (int _i = 0; _i < 2; ++_i) {    \
  int _a = aLow[_i] + (kc_) * 2048; _a ^= ((_a >> 13) & 3) << 5;              \
  af_[_i] = *(const short8*)(sIn + _a); } }

#define MM(buf, af_) { _Pragma("unroll") for (int _i = 0; _i < 2; ++_i)       \
  _Pragma("unroll") for (int _j = 0; _j < 8; ++_j)                            \
    acc[_i][_j] = __builtin_amdgcn_mfma_f32_16x16x32_bf16(af_[_i], buf[_j], acc[_i][_j], 0, 0, 0); }

#define BODY_L(kc_, buf, nbuf) { LDB(nbuf, (kc_) + 3);                        \
  short8 _af[2]; LDA(_af, kc_); MM(buf, _af); }
#define BODY_N(kc_, buf) { short8 _af[2]; LDA(_af, kc_); MM(buf, _af); }

// Batch-resident chain: one block = one batch element, all 6 steps.
// State (32x1024 bf16) ping-pongs between two 64KB LDS buffers (swizzled).
// B streams coalesced from L2 (frag-major nodeTf) through a 4-slot register
// ring (issue-to-use distance 3 bodies -> latency hidden, L2-BW-bound).
__global__ __launch_bounds__(512, 2) void entangler_batch(
    const float* __restrict__ x, const bf16* __restrict__ nodeTf,
    float* __restrict__ out, const float* __restrict__ bias) {
  extern __shared__ char smem[];
  char* st0 = smem;                // 65536 B: state buffer A
  char* st1 = smem + 65536;        // 65536 B: state buffer B

  const int t = threadIdx.x;
  const int lane = t & 63;
  const int lane16 = lane & 15, quad = lane >> 4;
  const int w = t >> 6;
  const int b = blockIdx.x;

  // ---- init: state0 logical byte (v*2048 + f*64 + u*2) <- x[b][u*1024+v*32+f]
  const float* xb = x + (size_t)b * DL3;
#pragma unroll
  for (int it = 0; it < 16; ++it) {
    int flat = it * 512 + t;
    floatx4 vx = *(const floatx4*)(xb + flat * 4);
    int e0 = flat * 4;
    int f = e0 & 31, v = (e0 >> 5) & 31, u = e0 >> 10;
#pragma unroll
    for (int e = 0; e < 4; ++e) {
      int byte = v * 2048 + (f + e) * 64 + u * 2;
      *(bf16*)(st0 + swz(byte)) = __float2bfloat16(vx[e]);
    }
  }

  // A-frag low address (f*64 + quad*16 with the bit7,8 swizzle term folded in;
  // the kc-dependent bit13,14 term is applied per body in LDA).
  int aLow[2];
#pragma unroll
  for (int i2 = 0; i2 < 2; ++i2) {
    int bb = (i2 * 16 + lane16) * 64 + quad * 16;
    aLow[i2] = bb ^ (((bb >> 7) & 3) << 4);
  }

  // per-thread coalesced B base: granule (nt = w*8 + j, lane), 16B/lane
  const char* Bb = (const char*)nodeTf + (size_t)((w * 8) * 512 + lane * 8) * 2;

  char* sIn = st0;
  char* sOut = st1;
  __syncthreads();   // init visible to all waves

#pragma unroll 1
  for (int s = 0; s < 6; ++s) {
    const char* Bs = Bb + (size_t)s * 2097152;

    floatx4 acc[2][8];
#pragma unroll
    for (int i2 = 0; i2 < 2; ++i2)
#pragma unroll
      for (int j = 0; j < 8; ++j)
        acc[i2][j] = (floatx4){0.f, 0.f, 0.f, 0.f};

    short8 bb0[8], bb1[8], bb2[8], bb3[8];
    LDB(bb0, 0); LDB(bb1, 1); LDB(bb2, 2);     // 3 chunks in flight (24 KB/wave)
#pragma unroll 1
    for (int kc0 = 0; kc0 < 28; kc0 += 4) {
      BODY_L(kc0 + 0, bb0, bb3);
      BODY_L(kc0 + 1, bb1, bb0);
      BODY_L(kc0 + 2, bb2, bb1);
      BODY_L(kc0 + 3, bb3, bb2);
    }
    BODY_L(28, bb0, bb3);                       // loads kc=31
    BODY_N(29, bb1);
    BODY_N(30, bb2);
    BODY_N(31, bb3);

    if (s < 5) {
      // epilogue -> LDS out buffer, logical byte = f_out*2048 + n*2, swizzled.
      // C/D layout: col = lane&15, row = quad*4 + reg  [m89-verified]
#pragma unroll
      for (int i2 = 0; i2 < 2; ++i2) {
#pragma unroll
        for (int j = 0; j < 8; ++j) {
#pragma unroll
          for (int r = 0; r < 4; ++r) {
            int f = i2 * 16 + quad * 4 + r;
            int n = w * 128 + j * 16 + lane16;
            int byte = f * 2048 + n * 2;
            *(bf16*)(sOut + swz(byte)) = __float2bfloat16(acc[i2][j][r]);
          }
        }
      }
      __syncthreads();   // publish new state; old state free to overwrite
      char* tmp = sIn; sIn = sOut; sOut = tmp;
    } else {
      // FINAL: out[b][f*1024+n] = relu(acc + bias[f*1024+n]), fp32
      float* ob = out + (size_t)b * DL3;
#pragma unroll
      for (int i2 = 0; i2 < 2; ++i2) {
#pragma unroll
        for (int j = 0; j < 8; ++j) {
#pragma unroll
          for (int r = 0; r < 4; ++r) {
            int f = i2 * 16 + quad * 4 + r;
            int n = w * 128 + j * 16 + lane16;
            float v = acc[i2][j][r] + bias[f * 1024 + n];
            ob[f * 1024 + n] = fmaxf(v, 0.f);
          }
        }
      }
    }
  }
}

extern "C" void kernel_launch(void* const* d_in, const int* in_sizes, int n_in,
                              void* d_out, int out_size, void* d_ws, size_t ws_size,
                              hipStream_t stream) {
  const float* x     = (const float*)d_in[0];   // (256, 32768) fp32
  const float* nodes = (const float*)d_in[1];   // (6, 32,32,32,32) fp32
  const float* bias  = (const float*)d_in[2];   // (32768,) fp32
  float* out = (float*)d_out;                   // (256, 32768) fp32

  // ws layout: nodeT 12MB | nodeTf 12MB
  bf16* nodeT  = (bf16*)d_ws;
  bf16* nodeTf = nodeT + (size_t)6 * 1048576;

  static bool attr_done = false;
  if (!attr_done) {
    hipFuncSetAttribute((const void*)entangler_batch,
                        hipFuncAttributeMaxDynamicSharedMemorySize, LDS_BYTES);
    attr_done = true;
  }

  prep_nodes<<<dim3(6 * 1024), dim3(256), 0, stream>>>(nodes, nodeT);
  prep_frag<<<dim3(6 * 32), dim3(256), 0, stream>>>(nodeT, nodeTf);
  entangler_batch<<<dim3(BATCH), dim3(512), LDS_BYTES, stream>>>(x, nodeTf, out, bias);
}